// Round 5
// baseline (375.229 us; speedup 1.0000x reference)
//
#include <hip/hip_runtime.h>

// Problem constants
#define G 4
#define M 4096
#define D 128
#define NQ 16384
#define NROWS 65536                      // total query rows (NQ * G)
#define OFF_IND 8388608                  // NROWS * D
#define OFF_CNT (OFF_IND + NROWS)
#define DELTA 0.02f

typedef unsigned int u32;
typedef unsigned short u16;
typedef __attribute__((ext_vector_type(8))) short bf16x8;
typedef __attribute__((ext_vector_type(4))) float f32x4;
typedef __attribute__((ext_vector_type(16))) float f32x16;

__device__ __forceinline__ u16 f2bf(float f) {
    u32 u = __float_as_uint(f);
    return (u16)((u + 0x7FFFu + ((u >> 16) & 1u)) >> 16);  // RNE
}
__device__ __forceinline__ float bf2f(u16 b) { return __uint_as_float((u32)b << 16); }

union bfpack { bf16x8 v; u32 u[4]; };

// ---------------- fast path ----------------

// e2both: exact fp64 row norms -> e2d (fp64, for recheck) + e2f (fp32, for vq).
// Also zeroes flagcnt (saves a memset dispatch).
__global__ __launch_bounds__(256) void e2both(const float* __restrict__ emb,
                                              float* __restrict__ e2f,
                                              double* __restrict__ e2d,
                                              int* __restrict__ flagcnt) {
    const int row = blockIdx.x * 4 + (threadIdx.x >> 6);
    const int lane = threadIdx.x & 63;
    const float2 v = ((const float2*)(emb + (size_t)row * D))[lane];
    double s = (double)v.x * (double)v.x + (double)v.y * (double)v.y;
#pragma unroll
    for (int off = 1; off < 64; off <<= 1) s += __shfl_xor(s, off, 64);
    if (lane == 0) { e2f[row] = (float)s; e2d[row] = s; }
    if (blockIdx.x == 0 && threadIdx.x == 0) *flagcnt = 0;
}

// efrag layout: chunk (g, mt) of 32 m's at (g*128+mt)*4096 u32 (16 KB).
// Within chunk: [(kk*2+h)*64 + lane] uint4; lane: m=mt*32+(lane&31), k=kk*16+(lane>>5)*8.
__global__ __launch_bounds__(256) void prep_emb(const float* __restrict__ emb,
                                                u32* __restrict__ efrag) {
    const int tid = threadIdx.x;
    const int g = blockIdx.x >> 7, mt = blockIdx.x & 127;
    u32* chunk = efrag + (size_t)(g * 128 + mt) * 4096;
#pragma unroll
    for (int rep = 0; rep < 2; ++rep) {
        const int idx = rep * 256 + tid;           // 0..511 -> (kk, lane)
        const int kk = idx >> 6, lane = idx & 63;
        const int m = mt * 32 + (lane & 31);
        const int k = kk * 16 + (lane >> 5) * 8;
        const float* src = emb + ((size_t)g * M + m) * D + k;
        const float4 a = *(const float4*)src;
        const float4 b = *(const float4*)(src + 4);
        const float v[8] = {a.x, a.y, a.z, a.w, b.x, b.y, b.z, b.w};
        u32 hi[4], lo[4];
#pragma unroll
        for (int i = 0; i < 4; ++i) {
            const float v0 = v[2 * i], v1 = v[2 * i + 1];
            const u16 h0 = f2bf(v0), h1 = f2bf(v1);
            const u16 l0 = f2bf(v0 - bf2f(h0)), l1 = f2bf(v1 - bf2f(h1));
            hi[i] = (u32)h0 | ((u32)h1 << 16);
            lo[i] = (u32)l0 | ((u32)l1 << 16);
        }
        *(uint4*)(chunk + (size_t)((kk * 2 + 0) * 64 + lane) * 4) = make_uint4(hi[0], hi[1], hi[2], hi[3]);
        *(uint4*)(chunk + (size_t)((kk * 2 + 1) * 64 + lane) * 4) = make_uint4(lo[0], lo[1], lo[2], lo[3]);
    }
}

// 32x32x16 MFMA distance+argmin. Block = (g, half, qb): 128 queries x 2048 m.
// Wave w owns 32 queries (one 32-row A tile); all waves share staged B chunks.
__global__ __launch_bounds__(256, 3) void vq_mfma3(const float* __restrict__ x,
                                                   const u32* __restrict__ efrag,
                                                   const float* __restrict__ e2f,
                                                   float* __restrict__ pb1,
                                                   float* __restrict__ pb2,
                                                   int* __restrict__ pi1) {
    __shared__ float e2s[2048];       // 8 KB
    __shared__ u32 ebuf[2][4096];     // 2 x 16 KB double buffer

    const int tid = threadIdx.x, w = tid >> 6, lane = tid & 63;
    const int combo = blockIdx.x & 7;              // XCD round-robin friendly
    const int g = combo >> 1, half = combo & 1;
    const int qb = blockIdx.x >> 3;                // 0..127

    const float* e2g = e2f + (size_t)g * M + half * 2048;
    for (int i = tid; i < 512; i += 256) ((float4*)e2s)[i] = ((const float4*)e2g)[i];

    // A fragments for this wave's 32 queries: row=lane&31, k=kk*16+(lane>>5)*8
    const int qrow = qb * 128 + w * 32 + (lane & 31);
    bf16x8 xh[8], xl[8];
#pragma unroll
    for (int kk = 0; kk < 8; ++kk) {
        const int k = kk * 16 + (lane >> 5) * 8;
        const float* src = x + ((size_t)qrow * 4 + g) * D + k;
        const float4 a = *(const float4*)src;
        const float4 b = *(const float4*)(src + 4);
        const float v[8] = {a.x, a.y, a.z, a.w, b.x, b.y, b.z, b.w};
        bfpack ph, pl;
#pragma unroll
        for (int i = 0; i < 4; ++i) {
            const float v0 = -2.0f * v[2 * i], v1 = -2.0f * v[2 * i + 1];
            const u16 h0 = f2bf(v0), h1 = f2bf(v1);
            const u16 l0 = f2bf(v0 - bf2f(h0)), l1 = f2bf(v1 - bf2f(h1));
            ph.u[i] = (u32)h0 | ((u32)h1 << 16);
            pl.u[i] = (u32)l0 | ((u32)l1 << 16);
        }
        xh[kk] = ph.v;
        xl[kk] = pl.v;
    }

    float b1[16], b2[16];
    int i1[16];
#pragma unroll
    for (int r = 0; r < 16; ++r) { b1[r] = 3.4e38f; b2[r] = 3.4e38f; i1[r] = 0; }

    const uint4* eg = (const uint4*)(efrag + (size_t)(g * 128 + half * 64) * 4096);
    {   // prologue: stage chunk 0
        const uint4 t0 = eg[tid], t1 = eg[256 + tid], t2 = eg[512 + tid], t3 = eg[768 + tid];
        uint4* db = (uint4*)ebuf[0];
        db[tid] = t0; db[256 + tid] = t1; db[512 + tid] = t2; db[768 + tid] = t3;
    }
    __syncthreads();

    for (int t = 0; t < 64; ++t) {
        const int cur = t & 1;
        uint4 s0, s1, s2, s3;
        if (t < 63) {                 // T14: issue next-chunk loads early
            const uint4* src = eg + (size_t)(t + 1) * 1024;
            s0 = src[tid]; s1 = src[256 + tid]; s2 = src[512 + tid]; s3 = src[768 + tid];
        }
        const bf16x8* bp = (const bf16x8*)ebuf[cur];
        const float e2c = e2s[t * 32 + (lane & 31)];
        f32x16 acc;
#pragma unroll
        for (int r = 0; r < 16; ++r) acc[r] = e2c;   // fold e2[m] into C-init
        __builtin_amdgcn_s_setprio(1);
#pragma unroll
        for (int kk = 0; kk < 8; ++kk) {
            const bf16x8 bh = bp[(kk * 2 + 0) * 64 + lane];
            const bf16x8 bl = bp[(kk * 2 + 1) * 64 + lane];
            acc = __builtin_amdgcn_mfma_f32_32x32x16_bf16(xl[kk], bh, acc, 0, 0, 0);
            acc = __builtin_amdgcn_mfma_f32_32x32x16_bf16(xh[kk], bl, acc, 0, 0, 0);
            acc = __builtin_amdgcn_mfma_f32_32x32x16_bf16(xh[kk], bh, acc, 0, 0, 0);
        }
        __builtin_amdgcn_s_setprio(0);
        const int mcol = half * 2048 + t * 32 + (lane & 31);
#pragma unroll
        for (int r = 0; r < 16; ++r) {
            const float s = acc[r];
            b2[r] = __builtin_amdgcn_fmed3f(s, b1[r], b2[r]);  // 2nd-best in 1 op
            i1[r] = (s < b1[r]) ? mcol : i1[r];
            b1[r] = fminf(b1[r], s);
        }
        if (t < 63) {                 // late LDS write of prefetched chunk
            uint4* db = (uint4*)ebuf[cur ^ 1];
            db[tid] = s0; db[256 + tid] = s1; db[512 + tid] = s2; db[768 + tid] = s3;
        }
        __syncthreads();
    }

    // reduce over the 32 m-lanes within each half-wave; lowest-index tie-break
#pragma unroll
    for (int r = 0; r < 16; ++r) {
        float v1 = b1[r], v2 = b2[r];
        int j1 = i1[r];
#pragma unroll
        for (int off = 1; off < 32; off <<= 1) {
            const float o1 = __shfl_xor(v1, off, 64);
            const int   oj = __shfl_xor(j1, off, 64);
            const float o2 = __shfl_xor(v2, off, 64);
            v2 = fminf(fminf(v2, o2), fmaxf(v1, o1));
            if (o1 < v1 || (o1 == v1 && oj < j1)) { v1 = o1; j1 = oj; }
        }
        if ((lane & 31) == 0) {
            const int q = qb * 128 + w * 32 + (r & 3) + 8 * (r >> 2) + 4 * (lane >> 5);
            const int pidx = ((((g << 14) | q)) << 1) | half;
            pb1[pidx] = v1;
            pb2[pidx] = v2;
            pi1[pidx] = j1;
        }
    }
}

// Combine the two m-halves per query; write index+count or flag for recheck.
__global__ __launch_bounds__(256) void merge_kernel(const float* __restrict__ pb1,
                                                    const float* __restrict__ pb2,
                                                    const int* __restrict__ pi1,
                                                    float* __restrict__ out,
                                                    int* __restrict__ flagcnt,
                                                    int* __restrict__ flaglist) {
    const int t = blockIdx.x * 256 + threadIdx.x;   // (g<<14)|n
    const float v1a = pb1[2 * t], v1b = pb1[2 * t + 1];
    const float v2a = pb2[2 * t], v2b = pb2[2 * t + 1];
    const int   ia = pi1[2 * t],  ib = pi1[2 * t + 1];
    const float v1 = fminf(v1a, v1b);
    const int   i  = (v1b < v1a) ? ib : ia;         // tie -> half0 (lower index)
    const float v2 = fminf(fminf(v2a, v2b), fmaxf(v1a, v1b));
    const int g = t >> 14, n = t & 16383;
    if (v2 - v1 > DELTA) {
        out[(size_t)OFF_IND + (size_t)n * 4 + g] = (float)i;
        atomicAdd(out + OFF_CNT + (size_t)g * M + i, 1.0f);
    } else {
        const int pos = atomicAdd(flagcnt, 1);
        flaglist[pos] = t;
    }
}

// exact fp64 rescan for flagged (near-tie) queries; uses precomputed exact e2d
__global__ __launch_bounds__(256) void recheck(const float* __restrict__ x,
                                               const float* __restrict__ emb,
                                               const double* __restrict__ e2d,
                                               const int* __restrict__ flagcnt,
                                               const int* __restrict__ flaglist,
                                               float* __restrict__ out) {
    __shared__ float xs[D];
    __shared__ double wv[4];
    __shared__ int wi[4];
    const int tid = threadIdx.x;
    int nf = *flagcnt;
    if (nf > NROWS) nf = NROWS;
    for (int it = blockIdx.x; it < nf; it += gridDim.x) {
        const int qid = flaglist[it];
        const int g = qid >> 14, n = qid & 16383;
        __syncthreads();
        if (tid < 32) ((float4*)xs)[tid] = ((const float4*)(x + ((size_t)n * 4 + g) * D))[tid];
        __syncthreads();
        double best = 1e300;
        int bi = 0;
        for (int j = 0; j < 16; ++j) {
            const int m = tid + j * 256;
            const float* e = emb + ((size_t)g * M + m) * D;
            double dot = 0.0;
            for (int k = 0; k < D; k += 4) {
                const float4 ev = *(const float4*)(e + k);
                dot = fma((double)xs[k + 0], (double)ev.x, dot);
                dot = fma((double)xs[k + 1], (double)ev.y, dot);
                dot = fma((double)xs[k + 2], (double)ev.z, dot);
                dot = fma((double)xs[k + 3], (double)ev.w, dot);
            }
            const double s = e2d[(size_t)g * M + m] - 2.0 * dot;
            if (s < best) { best = s; bi = m; }
        }
        for (int off = 1; off < 64; off <<= 1) {
            const double ob = __shfl_xor(best, off, 64);
            const int oi = __shfl_xor(bi, off, 64);
            if (ob < best || (ob == best && oi < bi)) { best = ob; bi = oi; }
        }
        if ((tid & 63) == 0) { wv[tid >> 6] = best; wi[tid >> 6] = bi; }
        __syncthreads();
        if (tid == 0) {
            double bv = wv[0];
            int bj = wi[0];
            for (int u = 1; u < 4; ++u)
                if (wv[u] < bv || (wv[u] == bv && wi[u] < bj)) { bv = wv[u]; bj = wi[u]; }
            out[(size_t)OFF_IND + (size_t)n * 4 + g] = (float)bj;
            atomicAdd(out + OFF_CNT + (size_t)g * M + bj, 1.0f);
        }
    }
}

__global__ __launch_bounds__(256) void gather_kernel(const float* __restrict__ emb,
                                                     const float* __restrict__ indf,
                                                     float* __restrict__ xq) {
    const int rid = blockIdx.x * 8 + (threadIdx.x >> 5);
    const int lane = threadIdx.x & 31;
    const int g = rid & 3;
    const int m = (int)indf[rid];
    const float4 v = ((const float4*)(emb + ((size_t)g * M + m) * D))[lane];
    ((float4*)(xq + (size_t)rid * D))[lane] = v;
}

// ---------------- fallback (exact fp64 path, used only if ws too small) ----------------

#define QT 64
#define MT 128
#define KT 32
#define XPAD 132
#define EPAD 36

__global__ __launch_bounds__(256) void e2d_kernel(const float* __restrict__ emb,
                                                  double* __restrict__ e2) {
    int row = blockIdx.x * 4 + (threadIdx.x >> 6);
    int lane = threadIdx.x & 63;
    const float2 v = ((const float2*)(emb + (size_t)row * D))[lane];
    double s = (double)v.x * (double)v.x + (double)v.y * (double)v.y;
#pragma unroll
    for (int off = 1; off < 64; off <<= 1) s += __shfl_xor(s, off, 64);
    if (lane == 0) e2[row] = s;
}

__global__ __launch_bounds__(256) void argmin_kernel(const float* __restrict__ x,
                                                     const float* __restrict__ emb,
                                                     const double* __restrict__ e2,
                                                     float* __restrict__ out) {
    __shared__ float xs[QT][XPAD];
    __shared__ float es[MT][EPAD];
    const int g = blockIdx.x >> 8;
    const int n0 = (blockIdx.x & 255) * QT;
    const int tid = threadIdx.x;
    const int tm = tid & 15;
    const int tq = tid >> 4;
#pragma unroll
    for (int it = 0; it < 8; ++it) {
        int idx = it * 256 + tid;
        int r = idx >> 5, c2 = idx & 31;
        const float4 v = ((const float4*)(x + ((size_t)((n0 + r) * 4 + g)) * D))[c2];
        *(float4*)&xs[r][c2 * 4] = v;
    }
    double best[4];
    int bm[4];
#pragma unroll
    for (int qi = 0; qi < 4; ++qi) { best[qi] = 1e300; bm[qi] = 0; }
    const double* e2g = e2 + (size_t)g * M;
    const float* eg = emb + (size_t)g * M * D;
    for (int mc = 0; mc < M / MT; ++mc) {
        const int m0 = mc * MT;
        double acc[4][8];
#pragma unroll
        for (int qi = 0; qi < 4; ++qi)
#pragma unroll
            for (int mi = 0; mi < 8; ++mi) acc[qi][mi] = 0.0;
        for (int kc = 0; kc < D / KT; ++kc) {
            __syncthreads();
#pragma unroll
            for (int it = 0; it < 4; ++it) {
                int idx = it * 256 + tid;
                int r = idx >> 3, c2 = idx & 7;
                const float4 v = ((const float4*)(eg + (size_t)(m0 + r) * D + kc * KT))[c2];
                *(float4*)&es[r][c2 * 4] = v;
            }
            __syncthreads();
#pragma unroll
            for (int kk = 0; kk < KT; kk += 4) {
                double xv[4][4];
#pragma unroll
                for (int qi = 0; qi < 4; ++qi) {
                    const float4 v = *(const float4*)&xs[tq + 16 * qi][kc * KT + kk];
                    xv[qi][0] = v.x; xv[qi][1] = v.y; xv[qi][2] = v.z; xv[qi][3] = v.w;
                }
#pragma unroll
                for (int mi = 0; mi < 8; ++mi) {
                    const float4 v = *(const float4*)&es[tm + 16 * mi][kk];
                    const double e0 = v.x, e1 = v.y, e2v = v.z, e3 = v.w;
#pragma unroll
                    for (int qi = 0; qi < 4; ++qi) {
                        acc[qi][mi] = fma(xv[qi][0], e0, acc[qi][mi]);
                        acc[qi][mi] = fma(xv[qi][1], e1, acc[qi][mi]);
                        acc[qi][mi] = fma(xv[qi][2], e2v, acc[qi][mi]);
                        acc[qi][mi] = fma(xv[qi][3], e3, acc[qi][mi]);
                    }
                }
            }
        }
#pragma unroll
        for (int mi = 0; mi < 8; ++mi) {
            const int m = m0 + tm + 16 * mi;
            const double e2m = e2g[m];
#pragma unroll
            for (int qi = 0; qi < 4; ++qi) {
                const double s = e2m - 2.0 * acc[qi][mi];
                if (s < best[qi]) { best[qi] = s; bm[qi] = m; }
            }
        }
    }
#pragma unroll
    for (int qi = 0; qi < 4; ++qi) {
        double v = best[qi];
        int i = bm[qi];
#pragma unroll
        for (int off = 1; off < 16; off <<= 1) {
            const double ov = __shfl_xor(v, off, 64);
            const int oi = __shfl_xor(i, off, 64);
            if (ov < v || (ov == v && oi < i)) { v = ov; i = oi; }
        }
        if (tm == 0) {
            const int n = n0 + tq + 16 * qi;
            out[(size_t)OFF_IND + (size_t)n * 4 + g] = (float)i;
            atomicAdd(out + OFF_CNT + (size_t)g * M + i, 1.0f);
        }
    }
}

// ---------------- launch ----------------

extern "C" void kernel_launch(void* const* d_in, const int* in_sizes, int n_in,
                              void* d_out, int out_size, void* d_ws, size_t ws_size,
                              hipStream_t stream) {
    const float* x   = (const float*)d_in[0];
    const float* emb = (const float*)d_in[1];
    const float* cnt = (const float*)d_in[2];
    float* out = (float*)d_out;

    if (ws_size >= 8454148) {
        u32*    efrag   = (u32*)d_ws;                          // [0, 8388608)
        float*  e2fp    = (float*)((char*)d_ws + 8388608);     // 64 KB
        int*    flagcnt = (int*)((char*)d_ws + 8454144);       // 4 B
        // scratch in the out buffer's x_quant region (overwritten by gather at the end)
        float*  pb1      = out;                                // 131072 f32
        float*  pb2      = out + 131072;
        int*    pi1      = (int*)(out + 262144);
        int*    flaglist = (int*)(out + 393216);               // 65536 ints
        double* e2d      = (double*)(out + 458752);            // 16384 f64 (8B-aligned)

        hipLaunchKernelGGL(e2both, dim3(4096), dim3(256), 0, stream, emb, e2fp, e2d, flagcnt);
        hipLaunchKernelGGL(prep_emb, dim3(512), dim3(256), 0, stream, emb, efrag);
        hipMemcpyAsync(out + OFF_CNT, cnt, (size_t)G * M * sizeof(float),
                       hipMemcpyDeviceToDevice, stream);
        hipLaunchKernelGGL(vq_mfma3, dim3(1024), dim3(256), 0, stream,
                           x, efrag, e2fp, pb1, pb2, pi1);
        hipLaunchKernelGGL(merge_kernel, dim3(256), dim3(256), 0, stream,
                           pb1, pb2, pi1, out, flagcnt, flaglist);
        hipLaunchKernelGGL(recheck, dim3(2048), dim3(256), 0, stream,
                           x, emb, e2d, flagcnt, flaglist, out);
        hipLaunchKernelGGL(gather_kernel, dim3(NROWS / 8), dim3(256), 0, stream,
                           emb, out + OFF_IND, out);
    } else {
        double* e2 = (double*)d_ws;
        hipLaunchKernelGGL(e2d_kernel, dim3(4096), dim3(256), 0, stream, emb, e2);
        hipMemcpyAsync(out + OFF_CNT, cnt, (size_t)G * M * sizeof(float),
                       hipMemcpyDeviceToDevice, stream);
        hipLaunchKernelGGL(argmin_kernel, dim3((NQ / QT) * G), dim3(256), 0, stream,
                           x, emb, e2, out);
        hipLaunchKernelGGL(gather_kernel, dim3(NROWS / 8), dim3(256), 0, stream,
                           emb, out + OFF_IND, out);
    }
}

// Round 6
// 366.285 us; speedup vs baseline: 1.0244x; 1.0244x over previous
//
#include <hip/hip_runtime.h>

// Problem constants
#define G 4
#define M 4096
#define D 128
#define NQ 16384
#define NROWS 65536                      // total query rows (NQ * G)
#define OFF_IND 8388608                  // NROWS * D
#define OFF_CNT (OFF_IND + NROWS)
#define DELTA 0.02f

typedef unsigned int u32;
typedef unsigned short u16;
typedef __attribute__((ext_vector_type(8))) short bf16x8;
typedef __attribute__((ext_vector_type(4))) float f32x4;
typedef __attribute__((ext_vector_type(16))) float f32x16;

__device__ __forceinline__ u16 f2bf(float f) {
    u32 u = __float_as_uint(f);
    return (u16)((u + 0x7FFFu + ((u >> 16) & 1u)) >> 16);  // RNE
}
__device__ __forceinline__ float bf2f(u16 b) { return __uint_as_float((u32)b << 16); }

union bfpack { bf16x8 v; u32 u[4]; };

// async global->LDS, 16B per lane; lds dst = wave-uniform base + lane*16 (HW)
__device__ __forceinline__ void gload16(const void* gsrc, void* ldsdst) {
    __builtin_amdgcn_global_load_lds(
        (const __attribute__((address_space(1))) u32*)gsrc,
        (__attribute__((address_space(3))) u32*)ldsdst,
        16, 0, 0);
}

// ---------------- fast path ----------------

// prep_all: emb -> efrag (hi/lo bf16 fragments) + e2f (fp32 row norms) + flagcnt=0.
// efrag chunk (g, mt) of 32 m's at (g*128+mt)*4096 u32 (16 KB), linear lane order.
__global__ __launch_bounds__(256) void prep_all(const float* __restrict__ emb,
                                                u32* __restrict__ efrag,
                                                float* __restrict__ e2f,
                                                int* __restrict__ flagcnt) {
    __shared__ float part[4][32];
    const int tid = threadIdx.x, w = tid >> 6;
    const int g = blockIdx.x >> 7, mt = blockIdx.x & 127;
    u32* chunk = efrag + (size_t)(g * 128 + mt) * 4096;
    float ss = 0.f;
#pragma unroll
    for (int rep = 0; rep < 2; ++rep) {
        const int idx = rep * 256 + tid;           // (kk, lane)
        const int kk = idx >> 6, lane = idx & 63;
        const int m = mt * 32 + (lane & 31);
        const int k = kk * 16 + (lane >> 5) * 8;
        const float* src = emb + ((size_t)g * M + m) * D + k;
        const float4 a = *(const float4*)src;
        const float4 b = *(const float4*)(src + 4);
        const float v[8] = {a.x, a.y, a.z, a.w, b.x, b.y, b.z, b.w};
#pragma unroll
        for (int i = 0; i < 8; ++i) ss = fmaf(v[i], v[i], ss);
        u32 hi[4], lo[4];
#pragma unroll
        for (int i = 0; i < 4; ++i) {
            const float v0 = v[2 * i], v1 = v[2 * i + 1];
            const u16 h0 = f2bf(v0), h1 = f2bf(v1);
            const u16 l0 = f2bf(v0 - bf2f(h0)), l1 = f2bf(v1 - bf2f(h1));
            hi[i] = (u32)h0 | ((u32)h1 << 16);
            lo[i] = (u32)l0 | ((u32)l1 << 16);
        }
        *(uint4*)(chunk + (size_t)((kk * 2 + 0) * 64 + lane) * 4) = make_uint4(hi[0], hi[1], hi[2], hi[3]);
        *(uint4*)(chunk + (size_t)((kk * 2 + 1) * 64 + lane) * 4) = make_uint4(lo[0], lo[1], lo[2], lo[3]);
    }
    // e2: thread covers 16 elems of row m; lanes l, l+32 share m (different k-half)
    ss += __shfl_xor(ss, 32, 64);
    if ((tid & 63) < 32) part[w][tid & 31] = ss;
    __syncthreads();
    if (tid < 32)
        e2f[(size_t)g * M + mt * 32 + tid] = part[0][tid] + part[1][tid] + part[2][tid] + part[3][tid];
    if (blockIdx.x == 0 && tid == 0) *flagcnt = 0;
}

// 32x32x16 MFMA distance+argmin. Block = (g, half, qb): 128 queries x 2048 m.
// global_load_lds staging; per-query partials written into that query's x_quant row.
__global__ __launch_bounds__(256, 3) void vq_mfma4(const float* __restrict__ x,
                                                   const u32* __restrict__ efrag,
                                                   const float* __restrict__ e2f,
                                                   float* __restrict__ out) {
    __shared__ float e2s[2048];       // 8 KB
    __shared__ u32 ebuf[2][4096];     // 2 x 16 KB double buffer

    const int tid = threadIdx.x, w = tid >> 6, lane = tid & 63;
    const int combo = blockIdx.x & 7;              // XCD round-robin friendly
    const int g = combo >> 1, half = combo & 1;
    const int qb = blockIdx.x >> 3;                // 0..127

    const float* e2g = e2f + (size_t)g * M + half * 2048;
    for (int i = tid; i < 512; i += 256) ((float4*)e2s)[i] = ((const float4*)e2g)[i];

    // A fragments for this wave's 32 queries: row=lane&31, k=kk*16+(lane>>5)*8
    const int qrow = qb * 128 + w * 32 + (lane & 31);
    bf16x8 xh[8], xl[8];
#pragma unroll
    for (int kk = 0; kk < 8; ++kk) {
        const int k = kk * 16 + (lane >> 5) * 8;
        const float* src = x + ((size_t)qrow * 4 + g) * D + k;
        const float4 a = *(const float4*)src;
        const float4 b = *(const float4*)(src + 4);
        const float v[8] = {a.x, a.y, a.z, a.w, b.x, b.y, b.z, b.w};
        bfpack ph, pl;
#pragma unroll
        for (int i = 0; i < 4; ++i) {
            const float v0 = -2.0f * v[2 * i], v1 = -2.0f * v[2 * i + 1];
            const u16 h0 = f2bf(v0), h1 = f2bf(v1);
            const u16 l0 = f2bf(v0 - bf2f(h0)), l1 = f2bf(v1 - bf2f(h1));
            ph.u[i] = (u32)h0 | ((u32)h1 << 16);
            pl.u[i] = (u32)l0 | ((u32)l1 << 16);
        }
        xh[kk] = ph.v;
        xl[kk] = pl.v;
    }

    float b1[16], b2[16];
    int i1[16];
#pragma unroll
    for (int r = 0; r < 16; ++r) { b1[r] = 3.4e38f; b2[r] = 3.4e38f; i1[r] = 0; }

    const char* eg = (const char*)(efrag + (size_t)(g * 128 + half * 64) * 4096);
    // prologue: stage chunk 0 via global_load_lds (linear, 4 x 16B per thread)
#pragma unroll
    for (int j = 0; j < 4; ++j)
        gload16(eg + j * 4096 + w * 1024 + lane * 16,
                (char*)ebuf[0] + j * 4096 + w * 1024);
    __syncthreads();   // drains vmcnt(0)

    int cur = 0;
    for (int t = 0; t < 64; ++t) {
        if (t < 63) {                 // issue next-chunk async loads early
            const char* src = eg + (size_t)(t + 1) * 16384;
#pragma unroll
            for (int j = 0; j < 4; ++j)
                gload16(src + j * 4096 + w * 1024 + lane * 16,
                        (char*)ebuf[cur ^ 1] + j * 4096 + w * 1024);
        }
        const bf16x8* bp = (const bf16x8*)ebuf[cur];
        const float e2c = e2s[t * 32 + (lane & 31)];
        f32x16 acc;
#pragma unroll
        for (int r = 0; r < 16; ++r) acc[r] = e2c;   // fold e2[m] into C-init
#pragma unroll
        for (int kk = 0; kk < 8; ++kk) {
            const bf16x8 bh = bp[(kk * 2 + 0) * 64 + lane];
            const bf16x8 bl = bp[(kk * 2 + 1) * 64 + lane];
            acc = __builtin_amdgcn_mfma_f32_32x32x16_bf16(xl[kk], bh, acc, 0, 0, 0);
            acc = __builtin_amdgcn_mfma_f32_32x32x16_bf16(xh[kk], bl, acc, 0, 0, 0);
            acc = __builtin_amdgcn_mfma_f32_32x32x16_bf16(xh[kk], bh, acc, 0, 0, 0);
        }
        const int mcol = half * 2048 + t * 32 + (lane & 31);
#pragma unroll
        for (int r = 0; r < 16; ++r) {
            const float s = acc[r];
            b2[r] = __builtin_amdgcn_fmed3f(s, b1[r], b2[r]);  // 2nd-best in 1 op
            i1[r] = (s < b1[r]) ? mcol : i1[r];
            b1[r] = fminf(b1[r], s);
        }
        __syncthreads();              // drains vmcnt(0): next chunk staged
        cur ^= 1;
    }

    // reduce over the 32 m-lanes within each half-wave; lowest-index tie-break.
    // Write per-query partial {v1, v2, idx} into the query's own x_quant row header.
#pragma unroll
    for (int r = 0; r < 16; ++r) {
        float v1 = b1[r], v2 = b2[r];
        int j1 = i1[r];
#pragma unroll
        for (int off = 1; off < 32; off <<= 1) {
            const float o1 = __shfl_xor(v1, off, 64);
            const int   oj = __shfl_xor(j1, off, 64);
            const float o2 = __shfl_xor(v2, off, 64);
            v2 = fminf(fminf(v2, o2), fmaxf(v1, o1));
            if (o1 < v1 || (o1 == v1 && oj < j1)) { v1 = o1; j1 = oj; }
        }
        if ((lane & 31) == 0) {
            const int q = qb * 128 + w * 32 + (r & 3) + 8 * (r >> 2) + 4 * (lane >> 5);
            float* rowbase = out + (size_t)(q * 4 + g) * D;
            *(float4*)(rowbase + half * 4) =
                make_float4(v1, v2, __int_as_float(j1), 0.f);
        }
    }
}

// gather_merge: per query merge the two half-partials (stored in its x_quant row),
// write ind + count (or flag), then gather the embedding row into x_quant.
__global__ __launch_bounds__(256) void gather_merge(const float* __restrict__ emb,
                                                    float* __restrict__ out,
                                                    int* __restrict__ flagcnt,
                                                    int* __restrict__ flaglist) {
    __shared__ int sm[64];
    const int tid = threadIdx.x;
    const int qid0 = blockIdx.x * 64;               // 64 queries per block, same g
    const int g = qid0 >> 14;
    if (tid < 64) {
        const int qid = qid0 + tid;
        const int n = qid & 16383;
        float* rowbase = out + (size_t)(n * 4 + g) * D;
        const float4 p0 = *(const float4*)(rowbase);
        const float4 p1 = *(const float4*)(rowbase + 4);
        const float v1a = p0.x, v2a = p0.y;
        const float v1b = p1.x, v2b = p1.y;
        const int ia = __float_as_int(p0.z), ib = __float_as_int(p1.z);
        const float v1 = fminf(v1a, v1b);
        const int i = (v1b < v1a) ? ib : ia;        // tie -> half0 (lower index)
        const float v2 = fminf(fminf(v2a, v2b), fmaxf(v1a, v1b));
        out[(size_t)OFF_IND + (size_t)n * 4 + g] = (float)i;   // approx for flagged
        if (v2 - v1 > DELTA) {
            atomicAdd(out + OFF_CNT + (size_t)g * M + i, 1.0f);
        } else {
            const int pos = atomicAdd(flagcnt, 1);
            flaglist[pos] = qid;                    // recheck fixes ind/count/row
        }
        sm[tid] = i;
    }
    __syncthreads();
#pragma unroll
    for (int p = 0; p < 8; ++p) {
        const int t2 = p * 8 + (tid >> 5);
        const int lane = tid & 31;
        const int n = (qid0 + t2) & 16383;
        const int m = sm[t2];
        const float4 v = ((const float4*)(emb + ((size_t)g * M + m) * D))[lane];
        ((float4*)(out + (size_t)(n * 4 + g) * D))[lane] = v;
    }
}

// exact fp64 rescan for flagged (near-tie) queries; also repairs x_quant row.
__global__ __launch_bounds__(256) void recheck2(const float* __restrict__ x,
                                                const float* __restrict__ emb,
                                                const int* __restrict__ flagcnt,
                                                const int* __restrict__ flaglist,
                                                float* __restrict__ out) {
    __shared__ float xs[D];
    __shared__ double wv[4];
    __shared__ int wi[4];
    __shared__ int sbj;
    const int tid = threadIdx.x;
    int nf = *flagcnt;
    if (nf > NROWS) nf = NROWS;
    for (int it = blockIdx.x; it < nf; it += gridDim.x) {
        const int qid = flaglist[it];
        const int g = qid >> 14, n = qid & 16383;
        __syncthreads();
        if (tid < 32) ((float4*)xs)[tid] = ((const float4*)(x + ((size_t)n * 4 + g) * D))[tid];
        __syncthreads();
        double best = 1e300;
        int bi = 0;
        for (int j = 0; j < 16; ++j) {
            const int m = tid + j * 256;
            const float* e = emb + ((size_t)g * M + m) * D;
            double dot = 0.0, ee = 0.0;
            for (int k = 0; k < D; k += 4) {
                const float4 ev = *(const float4*)(e + k);
                const double e0 = ev.x, e1 = ev.y, e2v = ev.z, e3 = ev.w;
                dot = fma((double)xs[k + 0], e0, dot);
                dot = fma((double)xs[k + 1], e1, dot);
                dot = fma((double)xs[k + 2], e2v, dot);
                dot = fma((double)xs[k + 3], e3, dot);
                ee = fma(e0, e0, ee); ee = fma(e1, e1, ee);
                ee = fma(e2v, e2v, ee); ee = fma(e3, e3, ee);
            }
            const double s = ee - 2.0 * dot;
            if (s < best) { best = s; bi = m; }
        }
        for (int off = 1; off < 64; off <<= 1) {
            const double ob = __shfl_xor(best, off, 64);
            const int oi = __shfl_xor(bi, off, 64);
            if (ob < best || (ob == best && oi < bi)) { best = ob; bi = oi; }
        }
        if ((tid & 63) == 0) { wv[tid >> 6] = best; wi[tid >> 6] = bi; }
        __syncthreads();
        if (tid == 0) {
            double bv = wv[0];
            int bj = wi[0];
            for (int u = 1; u < 4; ++u)
                if (wv[u] < bv || (wv[u] == bv && wi[u] < bj)) { bv = wv[u]; bj = wi[u]; }
            out[(size_t)OFF_IND + (size_t)n * 4 + g] = (float)bj;
            atomicAdd(out + OFF_CNT + (size_t)g * M + bj, 1.0f);
            sbj = bj;
        }
        __syncthreads();
        if (tid < 32) {
            const int bj = sbj;
            ((float4*)(out + (size_t)(n * 4 + g) * D))[tid] =
                ((const float4*)(emb + ((size_t)g * M + bj) * D))[tid];
        }
    }
}

// ---------------- fallback (exact fp64 path, used only if ws too small) ----------------

#define QT 64
#define MT 128
#define KT 32
#define XPAD 132
#define EPAD 36

__global__ __launch_bounds__(256) void e2d_kernel(const float* __restrict__ emb,
                                                  double* __restrict__ e2) {
    int row = blockIdx.x * 4 + (threadIdx.x >> 6);
    int lane = threadIdx.x & 63;
    const float2 v = ((const float2*)(emb + (size_t)row * D))[lane];
    double s = (double)v.x * (double)v.x + (double)v.y * (double)v.y;
#pragma unroll
    for (int off = 1; off < 64; off <<= 1) s += __shfl_xor(s, off, 64);
    if (lane == 0) e2[row] = s;
}

__global__ __launch_bounds__(256) void argmin_kernel(const float* __restrict__ x,
                                                     const float* __restrict__ emb,
                                                     const double* __restrict__ e2,
                                                     float* __restrict__ out) {
    __shared__ float xs[QT][XPAD];
    __shared__ float es[MT][EPAD];
    const int g = blockIdx.x >> 8;
    const int n0 = (blockIdx.x & 255) * QT;
    const int tid = threadIdx.x;
    const int tm = tid & 15;
    const int tq = tid >> 4;
#pragma unroll
    for (int it = 0; it < 8; ++it) {
        int idx = it * 256 + tid;
        int r = idx >> 5, c2 = idx & 31;
        const float4 v = ((const float4*)(x + ((size_t)((n0 + r) * 4 + g)) * D))[c2];
        *(float4*)&xs[r][c2 * 4] = v;
    }
    double best[4];
    int bm[4];
#pragma unroll
    for (int qi = 0; qi < 4; ++qi) { best[qi] = 1e300; bm[qi] = 0; }
    const double* e2g = e2 + (size_t)g * M;
    const float* eg = emb + (size_t)g * M * D;
    for (int mc = 0; mc < M / MT; ++mc) {
        const int m0 = mc * MT;
        double acc[4][8];
#pragma unroll
        for (int qi = 0; qi < 4; ++qi)
#pragma unroll
            for (int mi = 0; mi < 8; ++mi) acc[qi][mi] = 0.0;
        for (int kc = 0; kc < D / KT; ++kc) {
            __syncthreads();
#pragma unroll
            for (int it = 0; it < 4; ++it) {
                int idx = it * 256 + tid;
                int r = idx >> 3, c2 = idx & 7;
                const float4 v = ((const float4*)(eg + (size_t)(m0 + r) * D + kc * KT))[c2];
                *(float4*)&es[r][c2 * 4] = v;
            }
            __syncthreads();
#pragma unroll
            for (int kk = 0; kk < KT; kk += 4) {
                double xv[4][4];
#pragma unroll
                for (int qi = 0; qi < 4; ++qi) {
                    const float4 v = *(const float4*)&xs[tq + 16 * qi][kc * KT + kk];
                    xv[qi][0] = v.x; xv[qi][1] = v.y; xv[qi][2] = v.z; xv[qi][3] = v.w;
                }
#pragma unroll
                for (int mi = 0; mi < 8; ++mi) {
                    const float4 v = *(const float4*)&es[tm + 16 * mi][kk];
                    const double e0 = v.x, e1 = v.y, e2v = v.z, e3 = v.w;
#pragma unroll
                    for (int qi = 0; qi < 4; ++qi) {
                        acc[qi][mi] = fma(xv[qi][0], e0, acc[qi][mi]);
                        acc[qi][mi] = fma(xv[qi][1], e1, acc[qi][mi]);
                        acc[qi][mi] = fma(xv[qi][2], e2v, acc[qi][mi]);
                        acc[qi][mi] = fma(xv[qi][3], e3, acc[qi][mi]);
                    }
                }
            }
        }
#pragma unroll
        for (int mi = 0; mi < 8; ++mi) {
            const int m = m0 + tm + 16 * mi;
            const double e2m = e2g[m];
#pragma unroll
            for (int qi = 0; qi < 4; ++qi) {
                const double s = e2m - 2.0 * acc[qi][mi];
                if (s < best[qi]) { best[qi] = s; bm[qi] = m; }
            }
        }
    }
#pragma unroll
    for (int qi = 0; qi < 4; ++qi) {
        double v = best[qi];
        int i = bm[qi];
#pragma unroll
        for (int off = 1; off < 16; off <<= 1) {
            const double ov = __shfl_xor(v, off, 64);
            const int oi = __shfl_xor(i, off, 64);
            if (ov < v || (ov == v && oi < i)) { v = ov; i = oi; }
        }
        if (tm == 0) {
            const int n = n0 + tq + 16 * qi;
            out[(size_t)OFF_IND + (size_t)n * 4 + g] = (float)i;
            atomicAdd(out + OFF_CNT + (size_t)g * M + i, 1.0f);
        }
    }
}

__global__ __launch_bounds__(256) void gather_kernel(const float* __restrict__ emb,
                                                     const float* __restrict__ indf,
                                                     float* __restrict__ xq) {
    const int rid = blockIdx.x * 8 + (threadIdx.x >> 5);
    const int lane = threadIdx.x & 31;
    const int g = rid & 3;
    const int m = (int)indf[rid];
    const float4 v = ((const float4*)(emb + ((size_t)g * M + m) * D))[lane];
    ((float4*)(xq + (size_t)rid * D))[lane] = v;
}

// ---------------- launch ----------------

extern "C" void kernel_launch(void* const* d_in, const int* in_sizes, int n_in,
                              void* d_out, int out_size, void* d_ws, size_t ws_size,
                              hipStream_t stream) {
    const float* x   = (const float*)d_in[0];
    const float* emb = (const float*)d_in[1];
    const float* cnt = (const float*)d_in[2];
    float* out = (float*)d_out;

    if (ws_size >= 8716544) {
        u32*   efrag    = (u32*)d_ws;                          // [0, 8388608)
        float* e2fp     = (float*)((char*)d_ws + 8388608);     // 64 KB
        int*   flagcnt  = (int*)((char*)d_ws + 8454144);       // 4 B (pad 256)
        int*   flaglist = (int*)((char*)d_ws + 8454400);       // 256 KB -> end 8716544

        hipLaunchKernelGGL(prep_all, dim3(512), dim3(256), 0, stream,
                           emb, efrag, e2fp, flagcnt);
        hipMemcpyAsync(out + OFF_CNT, cnt, (size_t)G * M * sizeof(float),
                       hipMemcpyDeviceToDevice, stream);
        hipLaunchKernelGGL(vq_mfma4, dim3(1024), dim3(256), 0, stream,
                           x, efrag, e2fp, out);
        hipLaunchKernelGGL(gather_merge, dim3(1024), dim3(256), 0, stream,
                           emb, out, flagcnt, flaglist);
        hipLaunchKernelGGL(recheck2, dim3(2048), dim3(256), 0, stream,
                           x, emb, flagcnt, flaglist, out);
    } else {
        double* e2 = (double*)d_ws;
        hipLaunchKernelGGL(e2d_kernel, dim3(4096), dim3(256), 0, stream, emb, e2);
        hipMemcpyAsync(out + OFF_CNT, cnt, (size_t)G * M * sizeof(float),
                       hipMemcpyDeviceToDevice, stream);
        hipLaunchKernelGGL(argmin_kernel, dim3((NQ / QT) * G), dim3(256), 0, stream,
                           x, emb, e2, out);
        hipLaunchKernelGGL(gather_kernel, dim3(NROWS / 8), dim3(256), 0, stream,
                           emb, out + OFF_IND, out);
    }
}